// Round 1
// baseline (1131.042 us; speedup 1.0000x reference)
//
#include <hip/hip_runtime.h>

// Problem constants
#define BATCH 256
#define TT 1024
#define IN_DIM 96
#define NU 256
#define NC 10
#define EPS 0.01f
#define BETA 0.5f
#define GAMMA 0.0f
#define TWOLOG2E 2.8853900817779268f   // 2*log2(e): folded into Wa/Esw/Eb so
                                       // faccA is the exp2 argument directly

typedef _Float16 f16x8 __attribute__((ext_vector_type(8)));
typedef _Float16 f16x4 __attribute__((ext_vector_type(4)));
typedef float f32x4 __attribute__((ext_vector_type(4)));

// workspace layout (bytes)
// z: [t 1024][bb 16][bl 16][n 256] f16  (bb = batch/16 block = recur wg)
// per-lane z = S*(x@E^T + Eb) pre-scaled by TWOLOG2E
#define ZP_BYTES ((size_t)TT * 16 * 16 * 256 * 2)       // 134,217,728
#define WSW_OFF  ZP_BYTES
#define WSW_BYTES ((size_t)16384 * 16)                  // 262,144
#define ESW_OFF  (WSW_OFF + WSW_BYTES)

// ---------------------------------------------------------------------------
// prep_w v8: Wd = EPS*Dm, Wa = (16*2log2e)*A.
// Data layout is UNCHANGED vs v6: value(k = c*32+(l>>4)*8+j, n = ...+(l&15)).
// This same data now serves as the A-operand (W^T tile) of the swapped mfma:
// A-frag(row=l&15, k=(l>>4)*8+j) == B-frag(k, col=l&15) lane mapping.
// Flat: [w 8][mat 2][c 8][i 2][lane 64][8 halfs]
__global__ void prep_w(const float* __restrict__ C, const float* __restrict__ B,
                       _Float16* __restrict__ Wsw) {
    int u = blockIdx.x * 256 + threadIdx.x;   // 16384 units
    int l = u & 63;
    int i = (u >> 6) & 1;
    int c = (u >> 7) & 7;
    int mat = (u >> 10) & 1;
    int w = u >> 11;                          // 0..7
    int n = w * 32 + i * 16 + (l & 15);
    int kb = c * 32 + (l >> 4) * 8;
    const float* M = mat ? C : B;             // mat0: Dm from B; mat1: A from C
    float scale = mat ? (16.0f * TWOLOG2E) : EPS;
    f16x8 v;
#pragma unroll
    for (int j = 0; j < 8; j++) {
        int k = kb + j;
        float m1 = M[k * NU + n];
        float m2 = M[n * NU + k];
        float val = BETA * (m1 - m2) + (1.0f - BETA) * (m1 + m2)
                    - ((k == n) ? GAMMA : 0.0f);
        v[j] = (_Float16)(val * scale);
    }
    ((f16x8*)Wsw)[u] = v;
}

// ---------------------------------------------------------------------------
// prep_e v8: E_w scaled by 2log2e; layout unchanged (serves as swapped-mfma
// A-operand = E tile, row=unit, identical bytes).
// Flat: [w 4][c 3][i 4][lane 64][8 halfs]
__global__ void prep_e(const float* __restrict__ Ew, _Float16* __restrict__ Esw) {
    int u = blockIdx.x * 256 + threadIdx.x;   // 3072 units
    int l = u & 63;
    int i = (u >> 6) & 3;
    int wc = u >> 8;
    int c = wc % 3;
    int w = wc / 3;
    int n = w * 64 + i * 16 + (l & 15);
    int kb = c * 32 + (l >> 4) * 8;
    f16x8 v;
#pragma unroll
    for (int j = 0; j < 8; j++)
        v[j] = (_Float16)(Ew[n * IN_DIM + kb + j] * TWOLOG2E);
    ((f16x8*)Esw)[u] = v;
}

// ---------------------------------------------------------------------------
// zproj v8: swapped operands -> acc holds D[unit][batch]; lane(m,q) owns
// batch row m, units wz*64+i*16+q*4..+3 (k-consecutive) => b64 LDS writes
// into zt[bl][264] (conflict-free), ONE barrier per t, then fully-coalesced
// 32B global stores into the [bl][n] slab (offset = tid*16 halfs).
__global__ __launch_bounds__(256) void zproj(const float* __restrict__ x,
                                             const float* __restrict__ Eb,
                                             const _Float16* __restrict__ Esw,
                                             _Float16* __restrict__ zp) {
    __shared__ __align__(16) _Float16 zt[2][16 * 264];  // [bl][256 + pad8]
    int tid = threadIdx.x;
    int l = tid & 63, wz = tid >> 6, m = l & 15, q = l >> 4;
    int bb = blockIdx.x & 15, tb = blockIdx.x >> 4;
    int t0 = tb * 16, B0 = bb * 16;

    f16x8 ef[3][4];
    const f16x8* Ep = (const f16x8*)Esw;
#pragma unroll
    for (int c = 0; c < 3; c++)
#pragma unroll
        for (int i = 0; i < 4; i++)
            ef[c][i] = Ep[((wz * 3 + c) * 4 + i) * 64 + l];
    // bias per output-unit row (scaled): units wz*64 + i*16 + q*4 + r
    f32x4 ebv[4];
#pragma unroll
    for (int i = 0; i < 4; i++) {
        float4 b4 = *(const float4*)&Eb[wz * 64 + i * 16 + q * 4];
        f32x4 e4 = {b4.x * TWOLOG2E, b4.y * TWOLOG2E,
                    b4.z * TWOLOG2E, b4.w * TWOLOG2E};
        ebv[i] = e4;
    }

    // B-operand (x) source: x[b = B0+m][t][f = c*32 + q*8 + j] (unchanged)
    const float* xbase = x + (size_t)(B0 + m) * TT * IN_DIM + q * 8;

    for (int t = 0; t < 16; t++) {
        f16x8 af[3];
#pragma unroll
        for (int c = 0; c < 3; c++) {
            const float* px = xbase + (size_t)(t0 + t) * IN_DIM + c * 32;
            float4 v0 = *(const float4*)px;
            float4 v1 = *(const float4*)(px + 4);
            f16x8 a;
            a[0] = (_Float16)v0.x; a[1] = (_Float16)v0.y;
            a[2] = (_Float16)v0.z; a[3] = (_Float16)v0.w;
            a[4] = (_Float16)v1.x; a[5] = (_Float16)v1.y;
            a[6] = (_Float16)v1.z; a[7] = (_Float16)v1.w;
            af[c] = a;
        }
        f32x4 acc[4];
#pragma unroll
        for (int i = 0; i < 4; i++) acc[i] = ebv[i];
#pragma unroll
        for (int c = 0; c < 3; c++)
#pragma unroll
            for (int i = 0; i < 4; i++)
                acc[i] = __builtin_amdgcn_mfma_f32_16x16x32_f16(ef[c][i], af[c], acc[i], 0, 0, 0);

        // D[row = unit i*16+q*4+r][col = batch m] -> zt[m][wz*64+i*16+q*4..+3]
        _Float16* zb = zt[t & 1];
#pragma unroll
        for (int i = 0; i < 4; i++) {
            f16x4 o = {(_Float16)acc[i][0], (_Float16)acc[i][1],
                       (_Float16)acc[i][2], (_Float16)acc[i][3]};
            *(f16x4*)&zb[m * 264 + wz * 64 + i * 16 + q * 4] = o;
        }
        __syncthreads();
        // store: thread tid -> bl = tid>>4, n0 = (tid&15)*16 -> slab off tid*16
        {
            const _Float16* src = &zb[(tid >> 4) * 264 + (tid & 15) * 16];
            f16x8 s0 = *(const f16x8*)src;
            f16x8 s1 = *(const f16x8*)(src + 8);
            _Float16* dst = zp + (((size_t)(t0 + t) * 16 + bb) * 4096) + tid * 16;
            *(f16x8*)dst = s0;
            *(f16x8*)(dst + 8) = s1;
        }
        // no 2nd barrier: double buffer + next-t barrier orders reuse safely
    }
}

// ---------------------------------------------------------------------------
// Recurrence v8: swapped-operand MFMA. h stays in LDS as [b 16][264] halfs,
// read as B-frags (identical b128 pattern as v7's A-frags). Output C-layout
// is now D[unit][batch]: lane(m,q) holds batch m, units w*32+i*16+q*4..+3 =>
// h' write-back is 2x ds_write_b64, conflict-free (was 8x scalar b16, 4-way).
// Epilogue trimmed: exp2 arg pre-scaled (no mul), +EPS/16 folded into faccD
// init (no add): 5 VALU/elem incl 2 trans.

__device__ __forceinline__ void load_z2(f16x4 zc[2][2],
                                        const _Float16* __restrict__ zp,
                                        int tb, int wg, size_t voff0, size_t voff1) {
#pragma unroll
    for (int s = 0; s < 2; s++) {
        int ts = tb + s; ts = (ts > TT - 1) ? TT - 1 : ts;
        const _Float16* pz = zp + ((size_t)ts * 16 + wg) * 4096;
        zc[s][0] = *(const f16x4*)(pz + voff0);
        zc[s][1] = *(const f16x4*)(pz + voff1);
    }
}

__device__ __forceinline__ void step_fn(const _Float16* __restrict__ hb,
                                        _Float16* __restrict__ hn,
                                        const f16x8 wd[8][2], const f16x8 wa[8][2],
                                        float hm[8], const f16x4 zs[2],
                                        int m, int q, int w) {
    f32x4 faccD[2], faccA[2];
    f32x4 dinit = {EPS * 0.0625f, EPS * 0.0625f, EPS * 0.0625f, EPS * 0.0625f};
#pragma unroll
    for (int i = 0; i < 2; i++) {
        faccD[i] = dinit;                      // fold +EPS/16 into D-acc init
        f32x4 zi = {(float)zs[i][0], (float)zs[i][1],
                    (float)zs[i][2], (float)zs[i][3]};
        faccA[i] = zi;                         // z (pre-scaled by 2log2e)
    }

#pragma unroll
    for (int c = 0; c < 8; c++) {
        f16x8 af = *(const f16x8*)&hb[m * 264 + c * 32 + q * 8];
#pragma unroll
        for (int i = 0; i < 2; i++) {
            faccD[i] = __builtin_amdgcn_mfma_f32_16x16x32_f16(wd[c][i], af, faccD[i], 0, 0, 0);
            faccA[i] = __builtin_amdgcn_mfma_f32_16x16x32_f16(wa[c][i], af, faccA[i], 0, 0, 0);
        }
    }

#pragma unroll
    for (int i = 0; i < 2; i++) {
        f16x4 o;
#pragma unroll
        for (int r = 0; r < 4; r++) {
            float e = __builtin_amdgcn_exp2f(faccA[i][r]);   // 2^(2log2e*(hA+z))
            float R = __builtin_amdgcn_rcpf(e + 1.0f);
            float s = hm[i * 4 + r] + faccD[i][r];           // incl +EPS/16
            hm[i * 4 + r] = s - (2.0f * EPS * 0.0625f) * R;
            o[r] = (_Float16)hm[i * 4 + r];                  // h' = h/16
        }
        *(f16x4*)&hn[m * 264 + w * 32 + i * 16 + q * 4] = o; // b64, conflict-free
    }
    __syncthreads();
}

__global__ __launch_bounds__(512, 2) void recur(const _Float16* __restrict__ Wsw,
                                                const _Float16* __restrict__ zp,
                                                const float* __restrict__ Dw,
                                                const float* __restrict__ Db,
                                                float* __restrict__ out) {
    __shared__ __align__(16) _Float16 hbuf0[16 * 264];
    __shared__ __align__(16) _Float16 hbuf1[16 * 264];
    __shared__ float Yep[16 * 257];
    int tid = threadIdx.x;
    int l = tid & 63, w = tid >> 6, m = l & 15, q = l >> 4;
    int wg = blockIdx.x;

    // resident weight fragments: 32 f16x8 = 128 regs (AGPR-placed)
    f16x8 wd[8][2], wa[8][2];
    const f16x8* Wp = (const f16x8*)Wsw;
#pragma unroll
    for (int c = 0; c < 8; c++)
#pragma unroll
        for (int i = 0; i < 2; i++) {
            wd[c][i] = Wp[(((w * 2 + 0) * 8 + c) * 2 + i) * 64 + l];
            wa[c][i] = Wp[(((w * 2 + 1) * 8 + c) * 2 + i) * 64 + l];
        }
#pragma unroll
    for (int c = 0; c < 8; c++)
#pragma unroll
        for (int i = 0; i < 2; i++)
            asm volatile("" : "+v"(wd[c][i]), "+v"(wa[c][i]));

    float hm[8];
#pragma unroll
    for (int e = 0; e < 8; e++) hm[e] = 0.0f;
    for (int idx = tid; idx < 16 * 264; idx += 512) hbuf0[idx] = (_Float16)0.0f;

    // z element offsets within a (t, wg) slab [bl 16][n 256]:
    // lane(m,q): b = m, units w*32 + i*16 + q*4..+3
    size_t voff0 = (size_t)m * 256 + w * 32 + q * 4;
    size_t voff1 = voff0 + 16;                // i = 1
    f16x4 zA[2][2], zB[2][2];
    load_z2(zA, zp, 0, wg, voff0, voff1);
    load_z2(zB, zp, 2, wg, voff0, voff1);
    __syncthreads();

    for (int t = 0; t < TT; t += 4) {
        step_fn(hbuf0, hbuf1, wd, wa, hm, zA[0], m, q, w);
        step_fn(hbuf1, hbuf0, wd, wa, hm, zA[1], m, q, w);
        load_z2(zA, zp, t + 4, wg, voff0, voff1);   // drains at next barrier
        step_fn(hbuf0, hbuf1, wd, wa, hm, zB[0], m, q, w);
        step_fn(hbuf1, hbuf0, wd, wa, hm, zB[1], m, q, w);
        load_z2(zB, zp, t + 6, wg, voff0, voff1);
    }

    // epilogue: out[b][c] = h[b][:] @ Dw[c][:] + Db[c]   (h = 16*hm')
    // lane(m,q) holds batch m, units w*32+i*16+q*4+r
#pragma unroll
    for (int i = 0; i < 2; i++)
#pragma unroll
        for (int r = 0; r < 4; r++)
            Yep[m * 257 + w * 32 + i * 16 + q * 4 + r] = 16.0f * hm[i * 4 + r];
    __syncthreads();
    if (tid < 160) {
        int rr = tid / 10, c = tid - rr * 10;
        float s = Db[c];
        for (int k = 0; k < 256; k++) s += Yep[rr * 257 + k] * Dw[c * 256 + k];
        out[(wg * 16 + rr) * 10 + c] = s;
    }
}

// ---------------------------------------------------------------------------
extern "C" void kernel_launch(void* const* d_in, const int* in_sizes, int n_in,
                              void* d_out, int out_size, void* d_ws, size_t ws_size,
                              hipStream_t stream) {
    const float* x  = (const float*)d_in[0];
    const float* Ew = (const float*)d_in[1];
    const float* Eb = (const float*)d_in[2];
    const float* C  = (const float*)d_in[3];
    const float* B  = (const float*)d_in[4];
    const float* Dw = (const float*)d_in[5];
    const float* Db = (const float*)d_in[6];
    float* out = (float*)d_out;

    char* ws = (char*)d_ws;
    _Float16* zp  = (_Float16*)(ws);
    _Float16* Wsw = (_Float16*)(ws + WSW_OFF);
    _Float16* Esw = (_Float16*)(ws + ESW_OFF);

    hipLaunchKernelGGL(prep_w, dim3(64), dim3(256), 0, stream, C, B, Wsw);
    hipLaunchKernelGGL(prep_e, dim3(12), dim3(256), 0, stream, Ew, Esw);
    hipLaunchKernelGGL(zproj, dim3(1024), dim3(256), 0, stream, x, Eb, Esw, zp);
    hipLaunchKernelGGL(recur, dim3(16), dim3(512), 0, stream, Wsw, zp, Dw, Db, out);
}